// Round 3
// baseline (830.732 us; speedup 1.0000x reference)
//
#include <hip/hip_runtime.h>
#include <math.h>

#define N_NODES 100000
#define N_EDGES 3200000
#define F_IN    128
#define F_HID   32
#define N_CLS   10

#define BKT     256                                   // dst-nodes per bucket
#define NB      ((N_NODES + BKT - 1) / BKT)           // 391 buckets
#define CHUNK   8192                                  // edges per binpass block
#define NBIN    ((N_EDGES + CHUNK - 1) / CHUNK)       // 391 blocks

// ---------------- Kernel A: a = x@W1+b1, b = x@W2, c = x@W3+b3 ----------------
__global__ __launch_bounds__(256) void gemm3_kernel(
    const float* __restrict__ x,
    const float* __restrict__ W1, const float* __restrict__ b1,
    const float* __restrict__ W2,
    const float* __restrict__ W3, const float* __restrict__ b3,
    float* __restrict__ a, float* __restrict__ b, float* __restrict__ c)
{
    __shared__ float Wl[3][F_IN][F_HID];   // 48 KB
    const int tid = threadIdx.x;

    float4* Wlv = (float4*)&Wl[0][0][0];
    for (int i = tid; i < 3 * F_IN * F_HID / 4; i += 256) {
        int m = i >> 10;
        int r = i & 1023;
        const float4* srcp = (m == 0) ? (const float4*)W1
                           : (m == 1) ? (const float4*)W2
                                      : (const float4*)W3;
        Wlv[i] = srcp[r];
    }
    __syncthreads();

    const int node = blockIdx.x * 64 + (tid >> 2);
    const int p    = tid & 3;
    if (node >= N_NODES) return;

    float acc[3][8];
#pragma unroll
    for (int m = 0; m < 3; ++m)
#pragma unroll
        for (int i = 0; i < 8; ++i) acc[m][i] = 0.f;

    const float4* xrow = (const float4*)(x + (size_t)node * F_IN);
#pragma unroll 4
    for (int kk = 0; kk < F_IN / 4; ++kk) {
        float4 xv = xrow[kk];
#pragma unroll
        for (int j = 0; j < 4; ++j) {
            const int k = 4 * kk + j;
            const float xk = (&xv.x)[j];
#pragma unroll
            for (int m = 0; m < 3; ++m) {
                float4 wa = *(const float4*)&Wl[m][k][p * 8];
                float4 wb = *(const float4*)&Wl[m][k][p * 8 + 4];
                acc[m][0] += xk * wa.x; acc[m][1] += xk * wa.y;
                acc[m][2] += xk * wa.z; acc[m][3] += xk * wa.w;
                acc[m][4] += xk * wb.x; acc[m][5] += xk * wb.y;
                acc[m][6] += xk * wb.z; acc[m][7] += xk * wb.w;
            }
        }
    }

#pragma unroll
    for (int i = 0; i < 8; ++i) {
        acc[0][i] += b1[p * 8 + i];
        acc[2][i] += b3[p * 8 + i];
    }

    const size_t base = (size_t)node * F_HID + p * 8;
    *(float4*)&a[base]     = make_float4(acc[0][0], acc[0][1], acc[0][2], acc[0][3]);
    *(float4*)&a[base + 4] = make_float4(acc[0][4], acc[0][5], acc[0][6], acc[0][7]);
    *(float4*)&b[base]     = make_float4(acc[1][0], acc[1][1], acc[1][2], acc[1][3]);
    *(float4*)&b[base + 4] = make_float4(acc[1][4], acc[1][5], acc[1][6], acc[1][7]);
    *(float4*)&c[base]     = make_float4(acc[2][0], acc[2][1], acc[2][2], acc[2][3]);
    *(float4*)&c[base + 4] = make_float4(acc[2][4], acc[2][5], acc[2][6], acc[2][7]);
}

// ---------------- bucket histogram (LDS-staged) ----------------
__global__ __launch_bounds__(256) void hist_kernel(
    const int* __restrict__ ei, unsigned int* __restrict__ gcnt)
{
    __shared__ unsigned int h[NB];
    const int tid = threadIdx.x;
    for (int i = tid; i < NB; i += 256) h[i] = 0u;
    __syncthreads();
    const long long e0 = (long long)blockIdx.x * CHUNK;
    const int ne = (int)min((long long)CHUNK, (long long)N_EDGES - e0);
    for (int i = tid; i < ne; i += 256)
        atomicAdd(&h[ei[N_EDGES + e0 + i] >> 8], 1u);
    __syncthreads();
    for (int i = tid; i < NB; i += 256)
        if (h[i]) atomicAdd(&gcnt[i], h[i]);
}

// ---------------- exclusive scan of 391 bucket counts (one block) ----------------
__global__ __launch_bounds__(512) void scan_kernel(
    const unsigned int* __restrict__ gcnt,
    unsigned int* __restrict__ gbase, unsigned int* __restrict__ gcur)
{
    __shared__ unsigned int s[512];
    const int t = threadIdx.x;
    const unsigned int v = (t < NB) ? gcnt[t] : 0u;
    s[t] = v;
    __syncthreads();
    for (int d = 1; d < 512; d <<= 1) {
        unsigned int tv = (t >= d) ? s[t - d] : 0u;
        __syncthreads();
        s[t] += tv;
        __syncthreads();
    }
    if (t < NB) {
        const unsigned int base = s[t] - v;
        gbase[t] = base;
        gcur[t]  = base;
    }
}

// ---------------- binpass: partition edges into dst-buckets ----------------
// record: x = (dst_local << 17) | src, y = bits(ew)
__global__ __launch_bounds__(256) void binpass_kernel(
    const int* __restrict__ ei, const float* __restrict__ ea,
    unsigned int* __restrict__ gcur, uint2* __restrict__ packed)
{
    __shared__ unsigned int h[NB], basel[NB], lofs[NB];
    const int tid = threadIdx.x;
    const long long e0 = (long long)blockIdx.x * CHUNK;
    const int ne = (int)min((long long)CHUNK, (long long)N_EDGES - e0);

    for (int i = tid; i < NB; i += 256) { h[i] = 0u; lofs[i] = 0u; }
    __syncthreads();
    for (int i = tid; i < ne; i += 256)
        atomicAdd(&h[ei[N_EDGES + e0 + i] >> 8], 1u);
    __syncthreads();
    for (int i = tid; i < NB; i += 256)
        basel[i] = h[i] ? atomicAdd(&gcur[i], h[i]) : 0u;
    __syncthreads();
    for (int i = tid; i < ne; i += 256) {
        const int   src = ei[e0 + i];
        const int   dst = ei[N_EDGES + e0 + i];
        const float ew  = ea[e0 + i];
        const int   bkt = dst >> 8;
        const unsigned int pos = basel[bkt] + atomicAdd(&lofs[bkt], 1u);
        packed[pos] = make_uint2(((unsigned int)(dst & 255) << 17) | (unsigned int)src,
                                 __float_as_uint(ew));
    }
}

// ---------------- accum: per-bucket LDS accumulation ----------------
// acc[dstl][0..31] = sum ew*b[src][f]; acc[dstl][32] = sum ew
__global__ __launch_bounds__(256) void accum_kernel(
    const uint2* __restrict__ packed,
    const unsigned int* __restrict__ gbase, const unsigned int* __restrict__ gend,
    const float* __restrict__ b,
    float* __restrict__ c, float* __restrict__ degw)
{
    __shared__ float acc[BKT][33];   // 33.8 KB, padded vs bank conflicts
    const int bkt = blockIdx.x;
    const int tid = threadIdx.x;

    for (int i = tid; i < BKT * 33; i += 256) ((float*)acc)[i] = 0.f;
    __syncthreads();

    const unsigned int s0 = gbase[bkt];
    const unsigned int e0 = gend[bkt];
    const int p = tid & 3;

    for (unsigned int u = s0 + (tid >> 2); u < e0; u += 64) {
        const uint2 pe = packed[u];
        const unsigned int src  = pe.x & 0x1FFFFu;
        const int          dstl = (int)(pe.x >> 17);
        const float        ew   = __uint_as_float(pe.y);
        const float4* bs = (const float4*)(b + (size_t)src * F_HID) + p * 2;
        const float4 v0 = bs[0], v1 = bs[1];
        float* ar = &acc[dstl][p * 8];
        atomicAdd(&ar[0], ew * v0.x);
        atomicAdd(&ar[1], ew * v0.y);
        atomicAdd(&ar[2], ew * v0.z);
        atomicAdd(&ar[3], ew * v0.w);
        atomicAdd(&ar[4], ew * v1.x);
        atomicAdd(&ar[5], ew * v1.y);
        atomicAdd(&ar[6], ew * v1.z);
        atomicAdd(&ar[7], ew * v1.w);
        if (p == 0) atomicAdd(&acc[dstl][32], ew);
    }
    __syncthreads();

    const int node0 = bkt * BKT;
    // c[n] -= acc (float4-vectorized, race-free: bucket owns its nodes)
    for (int i = tid; i < BKT * (F_HID / 4); i += 256) {
        const int nl = i >> 3, fq = i & 7;
        const int n  = node0 + nl;
        if (n < N_NODES) {
            float4* cp = (float4*)(c + (size_t)n * F_HID) + fq;
            float4 cv = *cp;
            const float* av = &acc[nl][fq * 4];
            cv.x -= av[0]; cv.y -= av[1]; cv.z -= av[2]; cv.w -= av[3];
            *cp = cv;
        }
    }
    for (int nl = tid; nl < BKT; nl += 256) {
        const int n = node0 + nl;
        if (n < N_NODES) degw[n] = acc[nl][32];
    }
}

// ---------------- fallback: direct atomic edge scatter ----------------
__global__ __launch_bounds__(256) void edge_scatter_kernel(
    const int* __restrict__ ei, const float* __restrict__ ea,
    const float* __restrict__ b,
    float* __restrict__ c, float* __restrict__ degw)
{
    const long long t = (long long)blockIdx.x * 256 + threadIdx.x;
    const int e = (int)(t >> 2);
    const int p = (int)(t & 3);
    if (e >= N_EDGES) return;

    const int src = ei[e];
    const int dst = ei[N_EDGES + e];
    const float ew = ea[e];

    const float4* bs = (const float4*)(b + (size_t)src * F_HID) + p * 2;
    float4 v0 = bs[0], v1 = bs[1];

    float* cd = c + (size_t)dst * F_HID + p * 8;
    unsafeAtomicAdd(&cd[0], -ew * v0.x);
    unsafeAtomicAdd(&cd[1], -ew * v0.y);
    unsafeAtomicAdd(&cd[2], -ew * v0.z);
    unsafeAtomicAdd(&cd[3], -ew * v0.w);
    unsafeAtomicAdd(&cd[4], -ew * v1.x);
    unsafeAtomicAdd(&cd[5], -ew * v1.y);
    unsafeAtomicAdd(&cd[6], -ew * v1.z);
    unsafeAtomicAdd(&cd[7], -ew * v1.w);
    if (p == 0) unsafeAtomicAdd(&degw[dst], ew);
}

// ---------------- finalize ----------------
__global__ __launch_bounds__(256) void finalize_kernel(
    const float* __restrict__ a, const float* __restrict__ c,
    const float* __restrict__ degw,
    const float* __restrict__ fc_w, const float* __restrict__ fc_b,
    float* __restrict__ out)
{
    __shared__ float Wf[N_CLS][F_HID];
    __shared__ float Bf[N_CLS];
    const int tid = threadIdx.x;
    for (int i = tid; i < N_CLS * F_HID; i += 256)
        ((float*)Wf)[i] = fc_w[i];
    if (tid < N_CLS) Bf[tid] = fc_b[tid];
    __syncthreads();

    const int n = blockIdx.x * 256 + tid;
    if (n >= N_NODES) return;

    const float dw = degw[n];
    const float4* av = (const float4*)(a + (size_t)n * F_HID);
    const float4* cv = (const float4*)(c + (size_t)n * F_HID);

    float h[F_HID];
#pragma unroll
    for (int i = 0; i < F_HID / 4; ++i) {
        float4 A = av[i], C = cv[i];
        float t0 = C.x + dw * A.x;
        float t1 = C.y + dw * A.y;
        float t2 = C.z + dw * A.z;
        float t3 = C.w + dw * A.w;
        h[4 * i + 0] = t0 > 0.f ? t0 : expm1f(t0);
        h[4 * i + 1] = t1 > 0.f ? t1 : expm1f(t1);
        h[4 * i + 2] = t2 > 0.f ? t2 : expm1f(t2);
        h[4 * i + 3] = t3 > 0.f ? t3 : expm1f(t3);
    }

    float logits[N_CLS];
    float mx = -1e30f;
#pragma unroll
    for (int j = 0; j < N_CLS; ++j) {
        float s = Bf[j];
#pragma unroll
        for (int f = 0; f < F_HID; ++f) s += h[f] * Wf[j][f];
        logits[j] = s;
        mx = fmaxf(mx, s);
    }
    float sum = 0.f;
#pragma unroll
    for (int j = 0; j < N_CLS; ++j) sum += expf(logits[j] - mx);
    const float lse = mx + logf(sum);

    float* o = out + (size_t)n * N_CLS;
#pragma unroll
    for (int j = 0; j < N_CLS; ++j) o[j] = logits[j] - lse;
}

extern "C" void kernel_launch(void* const* d_in, const int* in_sizes, int n_in,
                              void* d_out, int out_size, void* d_ws, size_t ws_size,
                              hipStream_t stream) {
    const float* x   = (const float*)d_in[0];
    const int*   ei  = (const int*)d_in[1];
    const float* ea  = (const float*)d_in[2];
    const float* W1  = (const float*)d_in[3];
    const float* b1  = (const float*)d_in[4];
    const float* W2  = (const float*)d_in[5];
    const float* W3  = (const float*)d_in[6];
    const float* b3  = (const float*)d_in[7];
    const float* fcw = (const float*)d_in[8];
    const float* fcb = (const float*)d_in[9];
    float* out = (float*)d_out;

    const size_t NF = (size_t)N_NODES * F_HID;
    float* a    = (float*)d_ws;
    float* b    = a + NF;
    float* c    = b + NF;
    float* degw = c + NF;
    unsigned int* gcnt  = (unsigned int*)(degw + N_NODES);   // 512-padded each
    unsigned int* gbase = gcnt + 512;
    unsigned int* gcur  = gbase + 512;
    uint2* packed = (uint2*)(gcur + 512);   // 8B-aligned (even word count before)

    const size_t need = ((size_t)(3 * NF + N_NODES + 3 * 512)) * 4
                      + (size_t)N_EDGES * 8;

    gemm3_kernel<<<(N_NODES + 63) / 64, 256, 0, stream>>>(
        x, W1, b1, W2, W3, b3, a, b, c);

    if (ws_size >= need) {
        hipMemsetAsync(gcnt, 0, NB * sizeof(unsigned int), stream);
        hist_kernel<<<NBIN, 256, 0, stream>>>(ei, gcnt);
        scan_kernel<<<1, 512, 0, stream>>>(gcnt, gbase, gcur);
        binpass_kernel<<<NBIN, 256, 0, stream>>>(ei, ea, gcur, packed);
        accum_kernel<<<NB, 256, 0, stream>>>(packed, gbase, gcur, b, c, degw);
    } else {
        hipMemsetAsync(degw, 0, N_NODES * sizeof(float), stream);
        edge_scatter_kernel<<<(int)(((long long)N_EDGES * 4 + 255) / 256), 256, 0, stream>>>(
            ei, ea, b, c, degw);
    }

    finalize_kernel<<<(N_NODES + 255) / 256, 256, 0, stream>>>(
        a, c, degw, fcw, fcb, out);
}

// Round 4
// 215.376 us; speedup vs baseline: 3.8571x; 3.8571x over previous
//
#include <hip/hip_runtime.h>
#include <math.h>

#define N_NODES 100000
#define N_EDGES 3200000
#define F_IN    128
#define F_HID   32
#define N_CLS   10

#define BKT     128                                   // dst-nodes per bucket
#define NB      ((N_NODES + BKT - 1) / BKT)           // 782 buckets
#define CHUNK   8192                                  // edges per binpass block
#define NBIN    ((N_EDGES + CHUNK - 1) / CHUNK)       // 391 blocks
#define CAP     6144                                  // LDS record capacity (mean 4092, +32 sigma)

// ---------------- Kernel A: a = x@W1+b1, b = x@W2, c = x@W3+b3 ----------------
__global__ __launch_bounds__(256) void gemm3_kernel(
    const float* __restrict__ x,
    const float* __restrict__ W1, const float* __restrict__ b1,
    const float* __restrict__ W2,
    const float* __restrict__ W3, const float* __restrict__ b3,
    float* __restrict__ a, float* __restrict__ b, float* __restrict__ c)
{
    __shared__ float Wl[3][F_IN][F_HID];   // 48 KB
    const int tid = threadIdx.x;

    float4* Wlv = (float4*)&Wl[0][0][0];
    for (int i = tid; i < 3 * F_IN * F_HID / 4; i += 256) {
        int m = i >> 10;
        int r = i & 1023;
        const float4* srcp = (m == 0) ? (const float4*)W1
                           : (m == 1) ? (const float4*)W2
                                      : (const float4*)W3;
        Wlv[i] = srcp[r];
    }
    __syncthreads();

    const int node = blockIdx.x * 64 + (tid >> 2);
    const int p    = tid & 3;
    if (node >= N_NODES) return;

    float acc[3][8];
#pragma unroll
    for (int m = 0; m < 3; ++m)
#pragma unroll
        for (int i = 0; i < 8; ++i) acc[m][i] = 0.f;

    const float4* xrow = (const float4*)(x + (size_t)node * F_IN);
#pragma unroll 4
    for (int kk = 0; kk < F_IN / 4; ++kk) {
        float4 xv = xrow[kk];
#pragma unroll
        for (int j = 0; j < 4; ++j) {
            const int k = 4 * kk + j;
            const float xk = (&xv.x)[j];
#pragma unroll
            for (int m = 0; m < 3; ++m) {
                float4 wa = *(const float4*)&Wl[m][k][p * 8];
                float4 wb = *(const float4*)&Wl[m][k][p * 8 + 4];
                acc[m][0] += xk * wa.x; acc[m][1] += xk * wa.y;
                acc[m][2] += xk * wa.z; acc[m][3] += xk * wa.w;
                acc[m][4] += xk * wb.x; acc[m][5] += xk * wb.y;
                acc[m][6] += xk * wb.z; acc[m][7] += xk * wb.w;
            }
        }
    }

#pragma unroll
    for (int i = 0; i < 8; ++i) {
        acc[0][i] += b1[p * 8 + i];
        acc[2][i] += b3[p * 8 + i];
    }

    const size_t base = (size_t)node * F_HID + p * 8;
    *(float4*)&a[base]     = make_float4(acc[0][0], acc[0][1], acc[0][2], acc[0][3]);
    *(float4*)&a[base + 4] = make_float4(acc[0][4], acc[0][5], acc[0][6], acc[0][7]);
    *(float4*)&b[base]     = make_float4(acc[1][0], acc[1][1], acc[1][2], acc[1][3]);
    *(float4*)&b[base + 4] = make_float4(acc[1][4], acc[1][5], acc[1][6], acc[1][7]);
    *(float4*)&c[base]     = make_float4(acc[2][0], acc[2][1], acc[2][2], acc[2][3]);
    *(float4*)&c[base + 4] = make_float4(acc[2][4], acc[2][5], acc[2][6], acc[2][7]);
}

// ---------------- bucket histogram (LDS-staged) ----------------
__global__ __launch_bounds__(256) void hist_kernel(
    const int* __restrict__ ei, unsigned int* __restrict__ gcnt)
{
    __shared__ unsigned int h[NB];
    const int tid = threadIdx.x;
    for (int i = tid; i < NB; i += 256) h[i] = 0u;
    __syncthreads();
    const long long e0 = (long long)blockIdx.x * CHUNK;
    const int ne = (int)min((long long)CHUNK, (long long)N_EDGES - e0);
    for (int i = tid; i < ne; i += 256)
        atomicAdd(&h[ei[N_EDGES + e0 + i] >> 7], 1u);
    __syncthreads();
    for (int i = tid; i < NB; i += 256)
        if (h[i]) atomicAdd(&gcnt[i], h[i]);
}

// ---------------- exclusive scan of NB bucket counts (one block, 1024 thr) ----------------
__global__ __launch_bounds__(1024) void scan_kernel(
    const unsigned int* __restrict__ gcnt,
    unsigned int* __restrict__ gbase, unsigned int* __restrict__ gcur)
{
    __shared__ unsigned int s[1024];
    const int t = threadIdx.x;
    const unsigned int v = (t < NB) ? gcnt[t] : 0u;
    s[t] = v;
    __syncthreads();
    for (int d = 1; d < 1024; d <<= 1) {
        unsigned int tv = (t >= d) ? s[t - d] : 0u;
        __syncthreads();
        s[t] += tv;
        __syncthreads();
    }
    if (t < NB) {
        const unsigned int base = s[t] - v;
        gbase[t] = base;
        gcur[t]  = base;
    }
    if (t == 0) gbase[NB] = (unsigned int)N_EDGES;
}

// ---------------- binpass: partition edges into dst-buckets ----------------
// record: x = (dst_local << 17) | src, y = bits(ew)
__global__ __launch_bounds__(256) void binpass_kernel(
    const int* __restrict__ ei, const float* __restrict__ ea,
    unsigned int* __restrict__ gcur, uint2* __restrict__ packed)
{
    __shared__ unsigned int h[NB], basel[NB], lofs[NB];
    const int tid = threadIdx.x;
    const long long e0 = (long long)blockIdx.x * CHUNK;
    const int ne = (int)min((long long)CHUNK, (long long)N_EDGES - e0);

    for (int i = tid; i < NB; i += 256) { h[i] = 0u; lofs[i] = 0u; }
    __syncthreads();
    for (int i = tid; i < ne; i += 256)
        atomicAdd(&h[ei[N_EDGES + e0 + i] >> 7], 1u);
    __syncthreads();
    for (int i = tid; i < NB; i += 256)
        basel[i] = h[i] ? atomicAdd(&gcur[i], h[i]) : 0u;
    __syncthreads();
    for (int i = tid; i < ne; i += 256) {
        const int   src = ei[e0 + i];
        const int   dst = ei[N_EDGES + e0 + i];
        const float ew  = ea[e0 + i];
        const int   bkt = dst >> 7;
        const unsigned int pos = basel[bkt] + atomicAdd(&lofs[bkt], 1u);
        packed[pos] = make_uint2(((unsigned int)(dst & 127) << 17) | (unsigned int)src,
                                 __float_as_uint(ew));
    }
}

// ---------------- sort_accum: in-LDS counting sort + race-free accumulate ----------------
__global__ __launch_bounds__(512) void sort_accum_kernel(
    const uint2* __restrict__ packed, const unsigned int* __restrict__ gbase,
    const float* __restrict__ b,
    float* __restrict__ c, float* __restrict__ degw)
{
    __shared__ uint2 lrec[CAP];                 // 48 KB
    __shared__ unsigned int cnt[BKT], scn[BKT], cur[BKT];
    __shared__ unsigned int base[BKT + 1];
    const int bkt = blockIdx.x;
    const int tid = threadIdx.x;

    const unsigned int s0 = gbase[bkt];
    const unsigned int e0 = gbase[bkt + 1];
    const int K = (int)(e0 - s0);

    if (tid < BKT) cnt[tid] = 0u;
    __syncthreads();

    // pass 1: count per local-dst
    for (int i = tid; i < K; i += 512)
        atomicAdd(&cnt[packed[s0 + i].x >> 17], 1u);
    __syncthreads();

    // exclusive scan of cnt[0..127]
    if (tid < BKT) scn[tid] = cnt[tid];
    __syncthreads();
    for (int d = 1; d < BKT; d <<= 1) {
        unsigned int tv = 0u;
        if (tid < BKT && tid >= d) tv = scn[tid - d];
        __syncthreads();
        if (tid < BKT) scn[tid] += tv;
        __syncthreads();
    }
    if (tid < BKT) {
        base[tid] = scn[tid] - cnt[tid];
        cur[tid]  = scn[tid] - cnt[tid];
    }
    if (tid == 0) base[BKT] = (unsigned int)K;
    __syncthreads();

    // pass 2: place records node-sorted into LDS
    for (int i = tid; i < K; i += 512) {
        const uint2 rec = packed[s0 + i];
        const int dstl  = (int)(rec.x >> 17);
        const unsigned int pos = atomicAdd(&cur[dstl], 1u);
        if (pos < CAP) {
            lrec[pos] = rec;
        } else {
            // overflow safety valve (statistically never taken)
            const unsigned int src = rec.x & 0x1FFFFu;
            const float ew = __uint_as_float(rec.y);
            const int node = bkt * BKT + dstl;
            for (int f = 0; f < F_HID; ++f)
                unsafeAtomicAdd(&c[(size_t)node * F_HID + f],
                                -ew * b[(size_t)src * F_HID + f]);
            unsafeAtomicAdd(&degw[node], ew);
        }
    }
    __syncthreads();

    // accumulate: quad (4 lanes) per node, 8 feats per lane, no atomics
    const int q = tid >> 2;
    const int p = tid & 3;
    const int node = bkt * BKT + q;
    if (node < N_NODES) {
        unsigned int jb = base[q], je = base[q + 1];
        if (jb > CAP) jb = CAP;
        if (je > CAP) je = CAP;
        float4 a0 = make_float4(0.f, 0.f, 0.f, 0.f);
        float4 a1 = make_float4(0.f, 0.f, 0.f, 0.f);
        float dw = 0.f;
        for (unsigned int j = jb; j < je; ++j) {
            const uint2 rec = lrec[j];            // broadcast within quad
            const float ew = __uint_as_float(rec.y);
            const float4* bs = (const float4*)(b + (size_t)(rec.x & 0x1FFFFu) * F_HID) + p * 2;
            const float4 v0 = bs[0], v1 = bs[1];
            a0.x += ew * v0.x; a0.y += ew * v0.y; a0.z += ew * v0.z; a0.w += ew * v0.w;
            a1.x += ew * v1.x; a1.y += ew * v1.y; a1.z += ew * v1.z; a1.w += ew * v1.w;
            dw += ew;
        }
        float4* cp = (float4*)(c + (size_t)node * F_HID) + p * 2;
        float4 c0 = cp[0], c1 = cp[1];
        c0.x -= a0.x; c0.y -= a0.y; c0.z -= a0.z; c0.w -= a0.w;
        c1.x -= a1.x; c1.y -= a1.y; c1.z -= a1.z; c1.w -= a1.w;
        cp[0] = c0; cp[1] = c1;
        if (p == 0) unsafeAtomicAdd(&degw[node], dw);
    }
}

// ---------------- fallback: direct atomic edge scatter ----------------
__global__ __launch_bounds__(256) void edge_scatter_kernel(
    const int* __restrict__ ei, const float* __restrict__ ea,
    const float* __restrict__ b,
    float* __restrict__ c, float* __restrict__ degw)
{
    const long long t = (long long)blockIdx.x * 256 + threadIdx.x;
    const int e = (int)(t >> 2);
    const int p = (int)(t & 3);
    if (e >= N_EDGES) return;

    const int src = ei[e];
    const int dst = ei[N_EDGES + e];
    const float ew = ea[e];

    const float4* bs = (const float4*)(b + (size_t)src * F_HID) + p * 2;
    float4 v0 = bs[0], v1 = bs[1];

    float* cd = c + (size_t)dst * F_HID + p * 8;
    unsafeAtomicAdd(&cd[0], -ew * v0.x);
    unsafeAtomicAdd(&cd[1], -ew * v0.y);
    unsafeAtomicAdd(&cd[2], -ew * v0.z);
    unsafeAtomicAdd(&cd[3], -ew * v0.w);
    unsafeAtomicAdd(&cd[4], -ew * v1.x);
    unsafeAtomicAdd(&cd[5], -ew * v1.y);
    unsafeAtomicAdd(&cd[6], -ew * v1.z);
    unsafeAtomicAdd(&cd[7], -ew * v1.w);
    if (p == 0) unsafeAtomicAdd(&degw[dst], ew);
}

// ---------------- finalize ----------------
__global__ __launch_bounds__(256) void finalize_kernel(
    const float* __restrict__ a, const float* __restrict__ c,
    const float* __restrict__ degw,
    const float* __restrict__ fc_w, const float* __restrict__ fc_b,
    float* __restrict__ out)
{
    __shared__ float Wf[N_CLS][F_HID];
    __shared__ float Bf[N_CLS];
    const int tid = threadIdx.x;
    for (int i = tid; i < N_CLS * F_HID; i += 256)
        ((float*)Wf)[i] = fc_w[i];
    if (tid < N_CLS) Bf[tid] = fc_b[tid];
    __syncthreads();

    const int n = blockIdx.x * 256 + tid;
    if (n >= N_NODES) return;

    const float dw = degw[n];
    const float4* av = (const float4*)(a + (size_t)n * F_HID);
    const float4* cv = (const float4*)(c + (size_t)n * F_HID);

    float h[F_HID];
#pragma unroll
    for (int i = 0; i < F_HID / 4; ++i) {
        float4 A = av[i], C = cv[i];
        float t0 = C.x + dw * A.x;
        float t1 = C.y + dw * A.y;
        float t2 = C.z + dw * A.z;
        float t3 = C.w + dw * A.w;
        h[4 * i + 0] = t0 > 0.f ? t0 : expm1f(t0);
        h[4 * i + 1] = t1 > 0.f ? t1 : expm1f(t1);
        h[4 * i + 2] = t2 > 0.f ? t2 : expm1f(t2);
        h[4 * i + 3] = t3 > 0.f ? t3 : expm1f(t3);
    }

    float logits[N_CLS];
    float mx = -1e30f;
#pragma unroll
    for (int j = 0; j < N_CLS; ++j) {
        float s = Bf[j];
#pragma unroll
        for (int f = 0; f < F_HID; ++f) s += h[f] * Wf[j][f];
        logits[j] = s;
        mx = fmaxf(mx, s);
    }
    float sum = 0.f;
#pragma unroll
    for (int j = 0; j < N_CLS; ++j) sum += expf(logits[j] - mx);
    const float lse = mx + logf(sum);

    float* o = out + (size_t)n * N_CLS;
#pragma unroll
    for (int j = 0; j < N_CLS; ++j) o[j] = logits[j] - lse;
}

extern "C" void kernel_launch(void* const* d_in, const int* in_sizes, int n_in,
                              void* d_out, int out_size, void* d_ws, size_t ws_size,
                              hipStream_t stream) {
    const float* x   = (const float*)d_in[0];
    const int*   ei  = (const int*)d_in[1];
    const float* ea  = (const float*)d_in[2];
    const float* W1  = (const float*)d_in[3];
    const float* b1  = (const float*)d_in[4];
    const float* W2  = (const float*)d_in[5];
    const float* W3  = (const float*)d_in[6];
    const float* b3  = (const float*)d_in[7];
    const float* fcw = (const float*)d_in[8];
    const float* fcb = (const float*)d_in[9];
    float* out = (float*)d_out;

    const size_t NF = (size_t)N_NODES * F_HID;
    float* a    = (float*)d_ws;
    float* b    = a + NF;
    float* c    = b + NF;
    float* degw = c + NF;
    unsigned int* gcnt  = (unsigned int*)(degw + N_NODES);   // 1024 each (NB=782 fits)
    unsigned int* gbase = gcnt + 1024;
    unsigned int* gcur  = gbase + 1024;
    uint2* packed = (uint2*)(gcur + 1024);   // 8B-aligned (even word count before)

    const size_t need = ((size_t)(3 * NF + N_NODES + 3 * 1024)) * 4
                      + (size_t)N_EDGES * 8;

    gemm3_kernel<<<(N_NODES + 63) / 64, 256, 0, stream>>>(
        x, W1, b1, W2, W3, b3, a, b, c);

    if (ws_size >= need) {
        hipMemsetAsync(gcnt, 0, NB * sizeof(unsigned int), stream);
        hipMemsetAsync(degw, 0, N_NODES * sizeof(float), stream);
        hist_kernel<<<NBIN, 256, 0, stream>>>(ei, gcnt);
        scan_kernel<<<1, 1024, 0, stream>>>(gcnt, gbase, gcur);
        binpass_kernel<<<NBIN, 256, 0, stream>>>(ei, ea, gcur, packed);
        sort_accum_kernel<<<NB, 512, 0, stream>>>(packed, gbase, b, c, degw);
    } else {
        hipMemsetAsync(degw, 0, N_NODES * sizeof(float), stream);
        edge_scatter_kernel<<<(int)(((long long)N_EDGES * 4 + 255) / 256), 256, 0, stream>>>(
            ei, ea, b, c, degw);
    }

    finalize_kernel<<<(N_NODES + 255) / 256, 256, 0, stream>>>(
        a, c, degw, fcw, fcb, out);
}

// Round 5
// 202.581 us; speedup vs baseline: 4.1007x; 1.0632x over previous
//
#include <hip/hip_runtime.h>
#include <math.h>

#define N_NODES 100000
#define N_EDGES 3200000
#define F_IN    128
#define F_HID   32
#define N_CLS   10

#define BKT     128                                   // dst-nodes per bucket
#define NB      ((N_NODES + BKT - 1) / BKT)           // 782 buckets
#define CHUNK   8192                                  // edges per binpass block
#define NBIN    ((N_EDGES + CHUNK - 1) / CHUNK)       // 391 blocks
#define CHUNK_H 4096                                  // edges per hist block
#define NBIN_H  ((N_EDGES + CHUNK_H - 1) / CHUNK_H)   // 782 blocks
#define CAP     6144                                  // LDS record batch capacity

// ---------------- Kernel A: a = x@W1+b1, b = x@W2, c = x@W3+b3 ----------------
__global__ __launch_bounds__(256) void gemm3_kernel(
    const float* __restrict__ x,
    const float* __restrict__ W1, const float* __restrict__ b1,
    const float* __restrict__ W2,
    const float* __restrict__ W3, const float* __restrict__ b3,
    float* __restrict__ a, float* __restrict__ b, float* __restrict__ c)
{
    __shared__ float Wl[3][F_IN][F_HID];   // 48 KB
    const int tid = threadIdx.x;

    float4* Wlv = (float4*)&Wl[0][0][0];
    for (int i = tid; i < 3 * F_IN * F_HID / 4; i += 256) {
        int m = i >> 10;
        int r = i & 1023;
        const float4* srcp = (m == 0) ? (const float4*)W1
                           : (m == 1) ? (const float4*)W2
                                      : (const float4*)W3;
        Wlv[i] = srcp[r];
    }
    __syncthreads();

    const int node = blockIdx.x * 64 + (tid >> 2);
    const int p    = tid & 3;
    if (node >= N_NODES) return;

    float acc[3][8];
#pragma unroll
    for (int m = 0; m < 3; ++m)
#pragma unroll
        for (int i = 0; i < 8; ++i) acc[m][i] = 0.f;

    const float4* xrow = (const float4*)(x + (size_t)node * F_IN);
#pragma unroll 4
    for (int kk = 0; kk < F_IN / 4; ++kk) {
        float4 xv = xrow[kk];
#pragma unroll
        for (int j = 0; j < 4; ++j) {
            const int k = 4 * kk + j;
            const float xk = (&xv.x)[j];
#pragma unroll
            for (int m = 0; m < 3; ++m) {
                float4 wa = *(const float4*)&Wl[m][k][p * 8];
                float4 wb = *(const float4*)&Wl[m][k][p * 8 + 4];
                acc[m][0] += xk * wa.x; acc[m][1] += xk * wa.y;
                acc[m][2] += xk * wa.z; acc[m][3] += xk * wa.w;
                acc[m][4] += xk * wb.x; acc[m][5] += xk * wb.y;
                acc[m][6] += xk * wb.z; acc[m][7] += xk * wb.w;
            }
        }
    }

#pragma unroll
    for (int i = 0; i < 8; ++i) {
        acc[0][i] += b1[p * 8 + i];
        acc[2][i] += b3[p * 8 + i];
    }

    const size_t base = (size_t)node * F_HID + p * 8;
    *(float4*)&a[base]     = make_float4(acc[0][0], acc[0][1], acc[0][2], acc[0][3]);
    *(float4*)&a[base + 4] = make_float4(acc[0][4], acc[0][5], acc[0][6], acc[0][7]);
    *(float4*)&b[base]     = make_float4(acc[1][0], acc[1][1], acc[1][2], acc[1][3]);
    *(float4*)&b[base + 4] = make_float4(acc[1][4], acc[1][5], acc[1][6], acc[1][7]);
    *(float4*)&c[base]     = make_float4(acc[2][0], acc[2][1], acc[2][2], acc[2][3]);
    *(float4*)&c[base + 4] = make_float4(acc[2][4], acc[2][5], acc[2][6], acc[2][7]);
}

// ---------------- bucket histogram (LDS-staged) ----------------
__global__ __launch_bounds__(256) void hist_kernel(
    const int* __restrict__ ei, unsigned int* __restrict__ gcnt)
{
    __shared__ unsigned int h[NB];
    const int tid = threadIdx.x;
    for (int i = tid; i < NB; i += 256) h[i] = 0u;
    __syncthreads();
    const long long e0 = (long long)blockIdx.x * CHUNK_H;
    const int ne = (int)min((long long)CHUNK_H, (long long)N_EDGES - e0);
    for (int i = tid; i < ne; i += 256)
        atomicAdd(&h[ei[N_EDGES + e0 + i] >> 7], 1u);
    __syncthreads();
    for (int i = tid; i < NB; i += 256)
        if (h[i]) atomicAdd(&gcnt[i], h[i]);
}

// ---------------- exclusive scan of NB bucket counts (one block, 1024 thr) ----------------
__global__ __launch_bounds__(1024) void scan_kernel(
    const unsigned int* __restrict__ gcnt,
    unsigned int* __restrict__ gbase, unsigned int* __restrict__ gcur)
{
    __shared__ unsigned int s[1024];
    const int t = threadIdx.x;
    const unsigned int v = (t < NB) ? gcnt[t] : 0u;
    s[t] = v;
    __syncthreads();
    for (int d = 1; d < 1024; d <<= 1) {
        unsigned int tv = (t >= d) ? s[t - d] : 0u;
        __syncthreads();
        s[t] += tv;
        __syncthreads();
    }
    if (t < NB) {
        const unsigned int base = s[t] - v;
        gbase[t] = base;
        gcur[t]  = base;
    }
    if (t == 0) gbase[NB] = (unsigned int)N_EDGES;
}

// ---------------- binpass: partition edges into dst-buckets (512 thr) ----------------
// record: x = (dst_local << 17) | src, y = bits(ew)
__global__ __launch_bounds__(512) void binpass_kernel(
    const int* __restrict__ ei, const float* __restrict__ ea,
    unsigned int* __restrict__ gcur, uint2* __restrict__ packed)
{
    __shared__ unsigned int h[NB], basel[NB], lofs[NB];
    const int tid = threadIdx.x;
    const long long e0 = (long long)blockIdx.x * CHUNK;
    const int ne = (int)min((long long)CHUNK, (long long)N_EDGES - e0);

    for (int i = tid; i < NB; i += 512) { h[i] = 0u; lofs[i] = 0u; }
    __syncthreads();
    for (int i = tid; i < ne; i += 512)
        atomicAdd(&h[ei[N_EDGES + e0 + i] >> 7], 1u);
    __syncthreads();
    for (int i = tid; i < NB; i += 512)
        basel[i] = h[i] ? atomicAdd(&gcur[i], h[i]) : 0u;
    __syncthreads();
    for (int i = tid; i < ne; i += 512) {
        const int   src = ei[e0 + i];
        const int   dst = ei[N_EDGES + e0 + i];
        const float ew  = ea[e0 + i];
        const int   bkt = dst >> 7;
        const unsigned int pos = basel[bkt] + atomicAdd(&lofs[bkt], 1u);
        packed[pos] = make_uint2(((unsigned int)(dst & 127) << 17) | (unsigned int)src,
                                 __float_as_uint(ew));
    }
}

// ---------------- sort_accum_fin: counting sort + accumulate + fused finalize ----------------
// Exact for any bucket size via CAP-sized batches (register accumulators persist).
__global__ __launch_bounds__(512) void sort_accum_fin_kernel(
    const uint2* __restrict__ packed, const unsigned int* __restrict__ gbase,
    const float* __restrict__ a, const float* __restrict__ b,
    const float* __restrict__ c,
    const float* __restrict__ fc_w, const float* __restrict__ fc_b,
    float* __restrict__ out)
{
    __shared__ uint2 lrec[CAP];                 // 48 KB
    __shared__ unsigned int cnt[BKT], scn[BKT], cur[BKT];
    __shared__ unsigned int base[BKT + 1];
    __shared__ float Wf[N_CLS][F_HID];
    __shared__ float Bf[N_CLS];
    const int bkt = blockIdx.x;
    const int tid = threadIdx.x;

    for (int i = tid; i < N_CLS * F_HID; i += 512)
        ((float*)Wf)[i] = fc_w[i];
    if (tid < N_CLS) Bf[tid] = fc_b[tid];

    const unsigned int s0 = gbase[bkt];
    const unsigned int e0 = gbase[bkt + 1];

    const int q = tid >> 2;
    const int p = tid & 3;
    const int node = bkt * BKT + q;

    float4 a0 = make_float4(0.f, 0.f, 0.f, 0.f);
    float4 a1 = make_float4(0.f, 0.f, 0.f, 0.f);
    float dw = 0.f;

    for (unsigned int s = s0; s < e0; ) {
        const int Kb = (int)min((unsigned int)CAP, e0 - s);

        if (tid < BKT) cnt[tid] = 0u;
        __syncthreads();
        for (int i = tid; i < Kb; i += 512)
            atomicAdd(&cnt[packed[s + i].x >> 17], 1u);
        __syncthreads();
        if (tid < BKT) scn[tid] = cnt[tid];
        __syncthreads();
        for (int d = 1; d < BKT; d <<= 1) {
            unsigned int tv = 0u;
            if (tid < BKT && tid >= d) tv = scn[tid - d];
            __syncthreads();
            if (tid < BKT) scn[tid] += tv;
            __syncthreads();
        }
        if (tid < BKT) {
            base[tid] = scn[tid] - cnt[tid];
            cur[tid]  = scn[tid] - cnt[tid];
        }
        if (tid == 0) base[BKT] = (unsigned int)Kb;
        __syncthreads();
        for (int i = tid; i < Kb; i += 512) {
            const uint2 rec = packed[s + i];      // L2-hot (just read in count pass)
            lrec[atomicAdd(&cur[rec.x >> 17], 1u)] = rec;   // pos < Kb <= CAP always
        }
        __syncthreads();

        // accumulate: quad per node, 8 feats per lane, zero atomics
        const unsigned int jb = base[q], je = base[q + 1];
        for (unsigned int j = jb; j < je; ++j) {
            const uint2 rec = lrec[j];            // broadcast within quad
            const float ew = __uint_as_float(rec.y);
            const float4* bs = (const float4*)(b + (size_t)(rec.x & 0x1FFFFu) * F_HID) + p * 2;
            const float4 v0 = bs[0], v1 = bs[1];
            a0.x += ew * v0.x; a0.y += ew * v0.y; a0.z += ew * v0.z; a0.w += ew * v0.w;
            a1.x += ew * v1.x; a1.y += ew * v1.y; a1.z += ew * v1.z; a1.w += ew * v1.w;
            dw += ew;
        }
        __syncthreads();                          // lrec reuse fence for next batch
        s += (unsigned int)Kb;
    }

    if (node >= N_NODES) return;                  // no barriers past this point

    // fused finalize: h = elu(c - acc + dw*a); FC; log_softmax
    const float4* av = (const float4*)(a + (size_t)node * F_HID) + p * 2;
    const float4* cv = (const float4*)(c + (size_t)node * F_HID) + p * 2;
    const float4 A0 = av[0], A1 = av[1], C0 = cv[0], C1 = cv[1];

    float h8[8];
    {
        float t0 = C0.x - a0.x + dw * A0.x;
        float t1 = C0.y - a0.y + dw * A0.y;
        float t2 = C0.z - a0.z + dw * A0.z;
        float t3 = C0.w - a0.w + dw * A0.w;
        float t4 = C1.x - a1.x + dw * A1.x;
        float t5 = C1.y - a1.y + dw * A1.y;
        float t6 = C1.z - a1.z + dw * A1.z;
        float t7 = C1.w - a1.w + dw * A1.w;
        h8[0] = t0 > 0.f ? t0 : expm1f(t0);
        h8[1] = t1 > 0.f ? t1 : expm1f(t1);
        h8[2] = t2 > 0.f ? t2 : expm1f(t2);
        h8[3] = t3 > 0.f ? t3 : expm1f(t3);
        h8[4] = t4 > 0.f ? t4 : expm1f(t4);
        h8[5] = t5 > 0.f ? t5 : expm1f(t5);
        h8[6] = t6 > 0.f ? t6 : expm1f(t6);
        h8[7] = t7 > 0.f ? t7 : expm1f(t7);
    }

    float lg[N_CLS];
#pragma unroll
    for (int j = 0; j < N_CLS; ++j) {
        const float* wr = &Wf[j][p * 8];
        float sm = 0.f;
#pragma unroll
        for (int i = 0; i < 8; ++i) sm += h8[i] * wr[i];
        sm += __shfl_xor(sm, 1, 4);
        sm += __shfl_xor(sm, 2, 4);
        lg[j] = sm + Bf[j];
    }

    float mx = lg[0];
#pragma unroll
    for (int j = 1; j < N_CLS; ++j) mx = fmaxf(mx, lg[j]);
    float se = 0.f;
#pragma unroll
    for (int j = 0; j < N_CLS; ++j) se += expf(lg[j] - mx);
    const float lse = mx + logf(se);

    if (p == 0) {
        float* o = out + (size_t)node * N_CLS;
#pragma unroll
        for (int j = 0; j < N_CLS; ++j) o[j] = lg[j] - lse;
    }
}

// ---------------- fallback: direct atomic edge scatter ----------------
__global__ __launch_bounds__(256) void edge_scatter_kernel(
    const int* __restrict__ ei, const float* __restrict__ ea,
    const float* __restrict__ b,
    float* __restrict__ c, float* __restrict__ degw)
{
    const long long t = (long long)blockIdx.x * 256 + threadIdx.x;
    const int e = (int)(t >> 2);
    const int p = (int)(t & 3);
    if (e >= N_EDGES) return;

    const int src = ei[e];
    const int dst = ei[N_EDGES + e];
    const float ew = ea[e];

    const float4* bs = (const float4*)(b + (size_t)src * F_HID) + p * 2;
    float4 v0 = bs[0], v1 = bs[1];

    float* cd = c + (size_t)dst * F_HID + p * 8;
    unsafeAtomicAdd(&cd[0], -ew * v0.x);
    unsafeAtomicAdd(&cd[1], -ew * v0.y);
    unsafeAtomicAdd(&cd[2], -ew * v0.z);
    unsafeAtomicAdd(&cd[3], -ew * v0.w);
    unsafeAtomicAdd(&cd[4], -ew * v1.x);
    unsafeAtomicAdd(&cd[5], -ew * v1.y);
    unsafeAtomicAdd(&cd[6], -ew * v1.z);
    unsafeAtomicAdd(&cd[7], -ew * v1.w);
    if (p == 0) unsafeAtomicAdd(&degw[dst], ew);
}

// ---------------- finalize (fallback path only) ----------------
__global__ __launch_bounds__(256) void finalize_kernel(
    const float* __restrict__ a, const float* __restrict__ c,
    const float* __restrict__ degw,
    const float* __restrict__ fc_w, const float* __restrict__ fc_b,
    float* __restrict__ out)
{
    __shared__ float Wf[N_CLS][F_HID];
    __shared__ float Bf[N_CLS];
    const int tid = threadIdx.x;
    for (int i = tid; i < N_CLS * F_HID; i += 256)
        ((float*)Wf)[i] = fc_w[i];
    if (tid < N_CLS) Bf[tid] = fc_b[tid];
    __syncthreads();

    const int n = blockIdx.x * 256 + tid;
    if (n >= N_NODES) return;

    const float dw = degw[n];
    const float4* av = (const float4*)(a + (size_t)n * F_HID);
    const float4* cv = (const float4*)(c + (size_t)n * F_HID);

    float h[F_HID];
#pragma unroll
    for (int i = 0; i < F_HID / 4; ++i) {
        float4 A = av[i], C = cv[i];
        float t0 = C.x + dw * A.x;
        float t1 = C.y + dw * A.y;
        float t2 = C.z + dw * A.z;
        float t3 = C.w + dw * A.w;
        h[4 * i + 0] = t0 > 0.f ? t0 : expm1f(t0);
        h[4 * i + 1] = t1 > 0.f ? t1 : expm1f(t1);
        h[4 * i + 2] = t2 > 0.f ? t2 : expm1f(t2);
        h[4 * i + 3] = t3 > 0.f ? t3 : expm1f(t3);
    }

    float logits[N_CLS];
    float mx = -1e30f;
#pragma unroll
    for (int j = 0; j < N_CLS; ++j) {
        float s = Bf[j];
#pragma unroll
        for (int f = 0; f < F_HID; ++f) s += h[f] * Wf[j][f];
        logits[j] = s;
        mx = fmaxf(mx, s);
    }
    float sum = 0.f;
#pragma unroll
    for (int j = 0; j < N_CLS; ++j) sum += expf(logits[j] - mx);
    const float lse = mx + logf(sum);

    float* o = out + (size_t)n * N_CLS;
#pragma unroll
    for (int j = 0; j < N_CLS; ++j) o[j] = logits[j] - lse;
}

extern "C" void kernel_launch(void* const* d_in, const int* in_sizes, int n_in,
                              void* d_out, int out_size, void* d_ws, size_t ws_size,
                              hipStream_t stream) {
    const float* x   = (const float*)d_in[0];
    const int*   ei  = (const int*)d_in[1];
    const float* ea  = (const float*)d_in[2];
    const float* W1  = (const float*)d_in[3];
    const float* b1  = (const float*)d_in[4];
    const float* W2  = (const float*)d_in[5];
    const float* W3  = (const float*)d_in[6];
    const float* b3  = (const float*)d_in[7];
    const float* fcw = (const float*)d_in[8];
    const float* fcb = (const float*)d_in[9];
    float* out = (float*)d_out;

    const size_t NF = (size_t)N_NODES * F_HID;
    float* a    = (float*)d_ws;
    float* b    = a + NF;
    float* c    = b + NF;
    float* degw = c + NF;
    unsigned int* gcnt  = (unsigned int*)(degw + N_NODES);   // 1024 each (NB=782 fits)
    unsigned int* gbase = gcnt + 1024;
    unsigned int* gcur  = gbase + 1024;
    uint2* packed = (uint2*)(gcur + 1024);   // 8B-aligned

    const size_t need = ((size_t)(3 * NF + N_NODES + 3 * 1024)) * 4
                      + (size_t)N_EDGES * 8;

    gemm3_kernel<<<(N_NODES + 63) / 64, 256, 0, stream>>>(
        x, W1, b1, W2, W3, b3, a, b, c);

    if (ws_size >= need) {
        hipMemsetAsync(gcnt, 0, NB * sizeof(unsigned int), stream);
        hist_kernel<<<NBIN_H, 256, 0, stream>>>(ei, gcnt);
        scan_kernel<<<1, 1024, 0, stream>>>(gcnt, gbase, gcur);
        binpass_kernel<<<NBIN, 512, 0, stream>>>(ei, ea, gcur, packed);
        sort_accum_fin_kernel<<<NB, 512, 0, stream>>>(
            packed, gbase, a, b, c, fcw, fcb, out);
    } else {
        hipMemsetAsync(degw, 0, N_NODES * sizeof(float), stream);
        edge_scatter_kernel<<<(int)(((long long)N_EDGES * 4 + 255) / 256), 256, 0, stream>>>(
            ei, ea, b, c, degw);
        finalize_kernel<<<(N_NODES + 255) / 256, 256, 0, stream>>>(
            a, c, degw, fcw, fcb, out);
    }
}

// Round 6
// 147.444 us; speedup vs baseline: 5.6342x; 1.3740x over previous
//
#include <hip/hip_runtime.h>
#include <math.h>

#define N_NODES 100000
#define N_EDGES 3200000
#define F_IN    128
#define F_HID   32
#define N_CLS   10

#define BKT     128                                   // dst-nodes per bucket
#define NB      ((N_NODES + BKT - 1) / BKT)           // 782 buckets
#define SLACK   4672                                  // records reserved per bucket (mean 4092, +9 sigma)
#define CHUNKP  12500                                 // edges per partition block
#define NBP     ((N_EDGES + CHUNKP - 1) / CHUNKP)     // 256 blocks (exactly 1/CU)

// bf16 pack (RNE) of two floats -> u32 (lo = first, hi = second)
__device__ inline unsigned int bfpack2(float lo, float hi) {
    unsigned int al = __float_as_uint(lo), ah = __float_as_uint(hi);
    al = (al + 0x7fffu + ((al >> 16) & 1u)) >> 16;
    ah = (ah + 0x7fffu + ((ah >> 16) & 1u)) & 0xffff0000u;
    return al | ah;
}
__device__ inline float bflo(unsigned int u) { return __uint_as_float(u << 16); }
__device__ inline float bfhi(unsigned int u) { return __uint_as_float(u & 0xffff0000u); }

// ---------------- Kernel A: a = x@W1+b1 (f32), b = x@W2 (bf16), c = x@W3+b3 (f32) ----------------
__global__ __launch_bounds__(256) void gemm3_kernel(
    const float* __restrict__ x,
    const float* __restrict__ W1, const float* __restrict__ b1,
    const float* __restrict__ W2,
    const float* __restrict__ W3, const float* __restrict__ b3,
    float* __restrict__ a, unsigned short* __restrict__ bbf, float* __restrict__ c)
{
    __shared__ float Wl[3][F_IN][F_HID];   // 48 KB
    const int tid = threadIdx.x;

    float4* Wlv = (float4*)&Wl[0][0][0];
    for (int i = tid; i < 3 * F_IN * F_HID / 4; i += 256) {
        int m = i >> 10;
        int r = i & 1023;
        const float4* srcp = (m == 0) ? (const float4*)W1
                           : (m == 1) ? (const float4*)W2
                                      : (const float4*)W3;
        Wlv[i] = srcp[r];
    }
    __syncthreads();

    const int node = blockIdx.x * 64 + (tid >> 2);
    const int p    = tid & 3;
    if (node >= N_NODES) return;

    float acc[3][8];
#pragma unroll
    for (int m = 0; m < 3; ++m)
#pragma unroll
        for (int i = 0; i < 8; ++i) acc[m][i] = 0.f;

    const float4* xrow = (const float4*)(x + (size_t)node * F_IN);
#pragma unroll 4
    for (int kk = 0; kk < F_IN / 4; ++kk) {
        float4 xv = xrow[kk];
#pragma unroll
        for (int j = 0; j < 4; ++j) {
            const int k = 4 * kk + j;
            const float xk = (&xv.x)[j];
#pragma unroll
            for (int m = 0; m < 3; ++m) {
                float4 wa = *(const float4*)&Wl[m][k][p * 8];
                float4 wb = *(const float4*)&Wl[m][k][p * 8 + 4];
                acc[m][0] += xk * wa.x; acc[m][1] += xk * wa.y;
                acc[m][2] += xk * wa.z; acc[m][3] += xk * wa.w;
                acc[m][4] += xk * wb.x; acc[m][5] += xk * wb.y;
                acc[m][6] += xk * wb.z; acc[m][7] += xk * wb.w;
            }
        }
    }

#pragma unroll
    for (int i = 0; i < 8; ++i) {
        acc[0][i] += b1[p * 8 + i];
        acc[2][i] += b3[p * 8 + i];
    }

    const size_t base = (size_t)node * F_HID + p * 8;
    *(float4*)&a[base]     = make_float4(acc[0][0], acc[0][1], acc[0][2], acc[0][3]);
    *(float4*)&a[base + 4] = make_float4(acc[0][4], acc[0][5], acc[0][6], acc[0][7]);
    *(float4*)&c[base]     = make_float4(acc[2][0], acc[2][1], acc[2][2], acc[2][3]);
    *(float4*)&c[base + 4] = make_float4(acc[2][4], acc[2][5], acc[2][6], acc[2][7]);
    uint4 bw;
    bw.x = bfpack2(acc[1][0], acc[1][1]);
    bw.y = bfpack2(acc[1][2], acc[1][3]);
    bw.z = bfpack2(acc[1][4], acc[1][5]);
    bw.w = bfpack2(acc[1][6], acc[1][7]);
    *(uint4*)(bbf + base) = bw;
}

// ---------------- init: zero degw, set gcur[i] = i*SLACK ----------------
__global__ __launch_bounds__(256) void init_kernel(
    float* __restrict__ degw, unsigned int* __restrict__ gcur)
{
    const int n = blockIdx.x * 256 + threadIdx.x;
    if (n < N_NODES) degw[n] = 0.f;
    if (n < NB) gcur[n] = (unsigned int)n * SLACK;
}

// ---------------- partition: edges -> dst-bucket regions (slack-allocated) ----------------
// record: x = (dst_local << 17) | src, y = bits(ew)
__global__ __launch_bounds__(1024) void partition_kernel(
    const int* __restrict__ ei, const float* __restrict__ ea,
    unsigned int* __restrict__ gcur, uint2* __restrict__ packed,
    const unsigned short* __restrict__ bbf,
    float* __restrict__ c, float* __restrict__ degw)
{
    __shared__ unsigned int h[NB], basel[NB], lofs[NB];
    const int tid = threadIdx.x;
    const long long e0 = (long long)blockIdx.x * CHUNKP;
    const int ne = (int)min((long long)CHUNKP, (long long)N_EDGES - e0);

    for (int i = tid; i < NB; i += 1024) { h[i] = 0u; lofs[i] = 0u; }
    __syncthreads();
    for (int i = tid; i < ne; i += 1024)
        atomicAdd(&h[ei[N_EDGES + e0 + i] >> 7], 1u);
    __syncthreads();
    for (int i = tid; i < NB; i += 1024)
        basel[i] = h[i] ? atomicAdd(&gcur[i], h[i]) : 0u;
    __syncthreads();
    for (int i = tid; i < ne; i += 1024) {
        const int   src = ei[e0 + i];
        const int   dst = ei[N_EDGES + e0 + i];
        const float ew  = ea[e0 + i];
        const int   bkt = dst >> 7;
        const unsigned int pos = basel[bkt] + atomicAdd(&lofs[bkt], 1u);
        if (pos < (unsigned int)(bkt + 1) * SLACK) {
            packed[pos] = make_uint2(((unsigned int)(dst & 127) << 17) | (unsigned int)src,
                                     __float_as_uint(ew));
        } else {
            // overflow valve (P ~ 1e-19 per input; exactness-preserving)
            for (int f = 0; f < F_HID; ++f)
                unsafeAtomicAdd(&c[(size_t)dst * F_HID + f],
                                -ew * bflo((unsigned int)bbf[(size_t)src * F_HID + f] << 16));
            unsafeAtomicAdd(&degw[dst], ew);
        }
    }
}

// ---------------- sort_accum_fin: counting sort + accumulate + fused finalize ----------------
__global__ __launch_bounds__(512) void sort_accum_fin_kernel(
    const uint2* __restrict__ packed, const unsigned int* __restrict__ gcur,
    const float* __restrict__ a, const unsigned short* __restrict__ bbf,
    const float* __restrict__ c, const float* __restrict__ degw,
    const float* __restrict__ fc_w, const float* __restrict__ fc_b,
    float* __restrict__ out)
{
    __shared__ uint2 lrec[SLACK];               // 37.4 KB
    __shared__ unsigned int cnt[BKT], scn[BKT], cur[BKT];
    __shared__ unsigned int base[BKT + 1];
    __shared__ float Wf[N_CLS][F_HID];
    __shared__ float Bf[N_CLS];
    const int bkt = blockIdx.x;
    const int tid = threadIdx.x;

    for (int i = tid; i < N_CLS * F_HID; i += 512)
        ((float*)Wf)[i] = fc_w[i];
    if (tid < N_CLS) Bf[tid] = fc_b[tid];

    const unsigned int s0  = (unsigned int)bkt * SLACK;
    const unsigned int cap = s0 + SLACK;
    unsigned int e0 = gcur[bkt];
    if (e0 > cap) e0 = cap;
    const int K = (int)(e0 - s0);

    if (tid < BKT) cnt[tid] = 0u;
    __syncthreads();

    for (int i = tid; i < K; i += 512)
        atomicAdd(&cnt[packed[s0 + i].x >> 17], 1u);
    __syncthreads();
    if (tid < BKT) scn[tid] = cnt[tid];
    __syncthreads();
    for (int d = 1; d < BKT; d <<= 1) {
        unsigned int tv = 0u;
        if (tid < BKT && tid >= d) tv = scn[tid - d];
        __syncthreads();
        if (tid < BKT) scn[tid] += tv;
        __syncthreads();
    }
    if (tid < BKT) {
        base[tid] = scn[tid] - cnt[tid];
        cur[tid]  = scn[tid] - cnt[tid];
    }
    if (tid == 0) base[BKT] = (unsigned int)K;
    __syncthreads();
    for (int i = tid; i < K; i += 512) {
        const uint2 rec = packed[s0 + i];         // L2-hot from count pass
        lrec[atomicAdd(&cur[rec.x >> 17], 1u)] = rec;
    }
    __syncthreads();

    const int q = tid >> 2;
    const int p = tid & 3;
    const int node = bkt * BKT + q;
    if (node >= N_NODES) return;                  // no barriers below

    float4 a0 = make_float4(0.f, 0.f, 0.f, 0.f);
    float4 a1 = make_float4(0.f, 0.f, 0.f, 0.f);
    float dw = degw[node];                        // overflow-valve contribution (usually 0)

    const unsigned int jb = base[q], je = base[q + 1];
    for (unsigned int j = jb; j < je; ++j) {
        const uint2 rec = lrec[j];                // broadcast within quad
        const float ew = __uint_as_float(rec.y);
        const uint4 bv = *(const uint4*)(bbf + (size_t)(rec.x & 0x1FFFFu) * F_HID + p * 8);
        a0.x += ew * bflo(bv.x); a0.y += ew * bfhi(bv.x);
        a0.z += ew * bflo(bv.y); a0.w += ew * bfhi(bv.y);
        a1.x += ew * bflo(bv.z); a1.y += ew * bfhi(bv.z);
        a1.z += ew * bflo(bv.w); a1.w += ew * bfhi(bv.w);
        dw += ew;
    }

    // fused finalize: h = elu(c - acc + dw*a); FC; log_softmax
    const float4* av = (const float4*)(a + (size_t)node * F_HID) + p * 2;
    const float4* cv = (const float4*)(c + (size_t)node * F_HID) + p * 2;
    const float4 A0 = av[0], A1 = av[1], C0 = cv[0], C1 = cv[1];

    float h8[8];
    {
        float t0 = C0.x - a0.x + dw * A0.x;
        float t1 = C0.y - a0.y + dw * A0.y;
        float t2 = C0.z - a0.z + dw * A0.z;
        float t3 = C0.w - a0.w + dw * A0.w;
        float t4 = C1.x - a1.x + dw * A1.x;
        float t5 = C1.y - a1.y + dw * A1.y;
        float t6 = C1.z - a1.z + dw * A1.z;
        float t7 = C1.w - a1.w + dw * A1.w;
        h8[0] = t0 > 0.f ? t0 : expm1f(t0);
        h8[1] = t1 > 0.f ? t1 : expm1f(t1);
        h8[2] = t2 > 0.f ? t2 : expm1f(t2);
        h8[3] = t3 > 0.f ? t3 : expm1f(t3);
        h8[4] = t4 > 0.f ? t4 : expm1f(t4);
        h8[5] = t5 > 0.f ? t5 : expm1f(t5);
        h8[6] = t6 > 0.f ? t6 : expm1f(t6);
        h8[7] = t7 > 0.f ? t7 : expm1f(t7);
    }

    float lg[N_CLS];
#pragma unroll
    for (int j = 0; j < N_CLS; ++j) {
        const float* wr = &Wf[j][p * 8];
        float sm = 0.f;
#pragma unroll
        for (int i = 0; i < 8; ++i) sm += h8[i] * wr[i];
        sm += __shfl_xor(sm, 1, 4);
        sm += __shfl_xor(sm, 2, 4);
        lg[j] = sm + Bf[j];
    }

    float mx = lg[0];
#pragma unroll
    for (int j = 1; j < N_CLS; ++j) mx = fmaxf(mx, lg[j]);
    float se = 0.f;
#pragma unroll
    for (int j = 0; j < N_CLS; ++j) se += expf(lg[j] - mx);
    const float lse = mx + logf(se);

    if (p == 0) {
        float* o = out + (size_t)node * N_CLS;
#pragma unroll
        for (int j = 0; j < N_CLS; ++j) o[j] = lg[j] - lse;
    }
}

// ---------------- fallback: direct atomic edge scatter (bf16 b) ----------------
__global__ __launch_bounds__(256) void edge_scatter_kernel(
    const int* __restrict__ ei, const float* __restrict__ ea,
    const unsigned short* __restrict__ bbf,
    float* __restrict__ c, float* __restrict__ degw)
{
    const long long t = (long long)blockIdx.x * 256 + threadIdx.x;
    const int e = (int)(t >> 2);
    const int p = (int)(t & 3);
    if (e >= N_EDGES) return;

    const int src = ei[e];
    const int dst = ei[N_EDGES + e];
    const float ew = ea[e];

    const uint4 bv = *(const uint4*)(bbf + (size_t)src * F_HID + p * 8);

    float* cd = c + (size_t)dst * F_HID + p * 8;
    unsafeAtomicAdd(&cd[0], -ew * bflo(bv.x));
    unsafeAtomicAdd(&cd[1], -ew * bfhi(bv.x));
    unsafeAtomicAdd(&cd[2], -ew * bflo(bv.y));
    unsafeAtomicAdd(&cd[3], -ew * bfhi(bv.y));
    unsafeAtomicAdd(&cd[4], -ew * bflo(bv.z));
    unsafeAtomicAdd(&cd[5], -ew * bfhi(bv.z));
    unsafeAtomicAdd(&cd[6], -ew * bflo(bv.w));
    unsafeAtomicAdd(&cd[7], -ew * bfhi(bv.w));
    if (p == 0) unsafeAtomicAdd(&degw[dst], ew);
}

// ---------------- finalize (fallback path only) ----------------
__global__ __launch_bounds__(256) void finalize_kernel(
    const float* __restrict__ a, const float* __restrict__ c,
    const float* __restrict__ degw,
    const float* __restrict__ fc_w, const float* __restrict__ fc_b,
    float* __restrict__ out)
{
    __shared__ float Wf[N_CLS][F_HID];
    __shared__ float Bf[N_CLS];
    const int tid = threadIdx.x;
    for (int i = tid; i < N_CLS * F_HID; i += 256)
        ((float*)Wf)[i] = fc_w[i];
    if (tid < N_CLS) Bf[tid] = fc_b[tid];
    __syncthreads();

    const int n = blockIdx.x * 256 + tid;
    if (n >= N_NODES) return;

    const float dw = degw[n];
    const float4* av = (const float4*)(a + (size_t)n * F_HID);
    const float4* cv = (const float4*)(c + (size_t)n * F_HID);

    float h[F_HID];
#pragma unroll
    for (int i = 0; i < F_HID / 4; ++i) {
        float4 A = av[i], C = cv[i];
        float t0 = C.x + dw * A.x;
        float t1 = C.y + dw * A.y;
        float t2 = C.z + dw * A.z;
        float t3 = C.w + dw * A.w;
        h[4 * i + 0] = t0 > 0.f ? t0 : expm1f(t0);
        h[4 * i + 1] = t1 > 0.f ? t1 : expm1f(t1);
        h[4 * i + 2] = t2 > 0.f ? t2 : expm1f(t2);
        h[4 * i + 3] = t3 > 0.f ? t3 : expm1f(t3);
    }

    float logits[N_CLS];
    float mx = -1e30f;
#pragma unroll
    for (int j = 0; j < N_CLS; ++j) {
        float s = Bf[j];
#pragma unroll
        for (int f = 0; f < F_HID; ++f) s += h[f] * Wf[j][f];
        logits[j] = s;
        mx = fmaxf(mx, s);
    }
    float sum = 0.f;
#pragma unroll
    for (int j = 0; j < N_CLS; ++j) sum += expf(logits[j] - mx);
    const float lse = mx + logf(sum);

    float* o = out + (size_t)n * N_CLS;
#pragma unroll
    for (int j = 0; j < N_CLS; ++j) o[j] = logits[j] - lse;
}

extern "C" void kernel_launch(void* const* d_in, const int* in_sizes, int n_in,
                              void* d_out, int out_size, void* d_ws, size_t ws_size,
                              hipStream_t stream) {
    const float* x   = (const float*)d_in[0];
    const int*   ei  = (const int*)d_in[1];
    const float* ea  = (const float*)d_in[2];
    const float* W1  = (const float*)d_in[3];
    const float* b1  = (const float*)d_in[4];
    const float* W2  = (const float*)d_in[5];
    const float* W3  = (const float*)d_in[6];
    const float* b3  = (const float*)d_in[7];
    const float* fcw = (const float*)d_in[8];
    const float* fcb = (const float*)d_in[9];
    float* out = (float*)d_out;

    const size_t NF = (size_t)N_NODES * F_HID;
    float* a             = (float*)d_ws;
    float* c             = a + NF;
    unsigned short* bbf  = (unsigned short*)(c + NF);
    float* degw          = (float*)(bbf + NF);
    unsigned int* gcur   = (unsigned int*)(degw + N_NODES);
    uint2* packed        = (uint2*)(gcur + 1024);   // all prior byte counts divisible by 8

    const size_t need = NF * 4 * 2 + NF * 2 + (size_t)N_NODES * 4 + 4096
                      + (size_t)NB * SLACK * 8;     // ~61.6 MB

    gemm3_kernel<<<(N_NODES + 63) / 64, 256, 0, stream>>>(
        x, W1, b1, W2, W3, b3, a, bbf, c);

    if (ws_size >= need) {
        init_kernel<<<(N_NODES + 255) / 256, 256, 0, stream>>>(degw, gcur);
        partition_kernel<<<NBP, 1024, 0, stream>>>(ei, ea, gcur, packed, bbf, c, degw);
        sort_accum_fin_kernel<<<NB, 512, 0, stream>>>(
            packed, gcur, a, bbf, c, degw, fcw, fcb, out);
    } else {
        init_kernel<<<(N_NODES + 255) / 256, 256, 0, stream>>>(degw, gcur);
        edge_scatter_kernel<<<(int)(((long long)N_EDGES * 4 + 255) / 256), 256, 0, stream>>>(
            ei, ea, bbf, c, degw);
        finalize_kernel<<<(N_NODES + 255) / 256, 256, 0, stream>>>(
            a, c, degw, fcw, fcb, out);
    }
}

// Round 7
// 136.177 us; speedup vs baseline: 6.1004x; 1.0827x over previous
//
#include <hip/hip_runtime.h>
#include <math.h>

#define N_NODES 100000
#define N_EDGES 3200000
#define F_IN    128
#define F_HID   32
#define N_CLS   10

#define BKT     128                                   // dst-nodes per bucket
#define NB      ((N_NODES + BKT - 1) / BKT)           // 782 buckets
#define SLACK   4672                                  // records reserved per bucket (mean 4092, +9 sigma)
#define CHUNKP  12500                                 // edges per partition block
#define NBP     ((N_EDGES + CHUNKP - 1) / CHUNKP)     // 256 blocks (exactly 1/CU)

// bf16 pack (RNE) of two floats -> u32 (lo = first, hi = second)
__device__ inline unsigned int bfpack2(float lo, float hi) {
    unsigned int al = __float_as_uint(lo), ah = __float_as_uint(hi);
    al = (al + 0x7fffu + ((al >> 16) & 1u)) >> 16;
    ah = (ah + 0x7fffu + ((ah >> 16) & 1u)) & 0xffff0000u;
    return al | ah;
}
__device__ inline float bflo(unsigned int u) { return __uint_as_float(u << 16); }
__device__ inline float bfhi(unsigned int u) { return __uint_as_float(u & 0xffff0000u); }

// ---------------- Kernel A: a = x@W1+b1 (f32), b = x@W2 (bf16), c = x@W3+b3 (f32) ----------------
// 2 nodes per thread (n0, n0+64): each LDS W-fragment read feeds 2x FMAs -> VALU-bound.
__global__ __launch_bounds__(256) void gemm3_kernel(
    const float* __restrict__ x,
    const float* __restrict__ W1, const float* __restrict__ b1,
    const float* __restrict__ W2,
    const float* __restrict__ W3, const float* __restrict__ b3,
    float* __restrict__ a, unsigned short* __restrict__ bbf, float* __restrict__ c)
{
    __shared__ float Wl[3][F_IN][F_HID];   // 48 KB
    const int tid = threadIdx.x;

    float4* Wlv = (float4*)&Wl[0][0][0];
    for (int i = tid; i < 3 * F_IN * F_HID / 4; i += 256) {
        int m = i >> 10;
        int r = i & 1023;
        const float4* srcp = (m == 0) ? (const float4*)W1
                           : (m == 1) ? (const float4*)W2
                                      : (const float4*)W3;
        Wlv[i] = srcp[r];
    }
    __syncthreads();

    const int q  = tid >> 2;                 // 0..63
    const int p  = tid & 3;
    const int n0 = blockIdx.x * 128 + q;
    const int n1 = n0 + 64;
    const bool v0 = n0 < N_NODES, v1 = n1 < N_NODES;

    float acc0[3][8], acc1[3][8];
#pragma unroll
    for (int m = 0; m < 3; ++m)
#pragma unroll
        for (int i = 0; i < 8; ++i) { acc0[m][i] = 0.f; acc1[m][i] = 0.f; }

    const float4* xr0 = (const float4*)(x + (size_t)(v0 ? n0 : 0) * F_IN);
    const float4* xr1 = (const float4*)(x + (size_t)(v1 ? n1 : 0) * F_IN);

#pragma unroll 4
    for (int kk = 0; kk < F_IN / 4; ++kk) {
        const float4 xv0 = xr0[kk];
        const float4 xv1 = xr1[kk];
#pragma unroll
        for (int j = 0; j < 4; ++j) {
            const int k = 4 * kk + j;
            const float xk0 = (&xv0.x)[j];
            const float xk1 = (&xv1.x)[j];
#pragma unroll
            for (int m = 0; m < 3; ++m) {
                const float4 wa = *(const float4*)&Wl[m][k][p * 8];
                const float4 wb = *(const float4*)&Wl[m][k][p * 8 + 4];
                acc0[m][0] += xk0 * wa.x; acc0[m][1] += xk0 * wa.y;
                acc0[m][2] += xk0 * wa.z; acc0[m][3] += xk0 * wa.w;
                acc0[m][4] += xk0 * wb.x; acc0[m][5] += xk0 * wb.y;
                acc0[m][6] += xk0 * wb.z; acc0[m][7] += xk0 * wb.w;
                acc1[m][0] += xk1 * wa.x; acc1[m][1] += xk1 * wa.y;
                acc1[m][2] += xk1 * wa.z; acc1[m][3] += xk1 * wa.w;
                acc1[m][4] += xk1 * wb.x; acc1[m][5] += xk1 * wb.y;
                acc1[m][6] += xk1 * wb.z; acc1[m][7] += xk1 * wb.w;
            }
        }
    }

    float bias1[8], bias3[8];
#pragma unroll
    for (int i = 0; i < 8; ++i) { bias1[i] = b1[p * 8 + i]; bias3[i] = b3[p * 8 + i]; }

    if (v0) {
        const size_t base = (size_t)n0 * F_HID + p * 8;
        *(float4*)&a[base]     = make_float4(acc0[0][0] + bias1[0], acc0[0][1] + bias1[1],
                                             acc0[0][2] + bias1[2], acc0[0][3] + bias1[3]);
        *(float4*)&a[base + 4] = make_float4(acc0[0][4] + bias1[4], acc0[0][5] + bias1[5],
                                             acc0[0][6] + bias1[6], acc0[0][7] + bias1[7]);
        *(float4*)&c[base]     = make_float4(acc0[2][0] + bias3[0], acc0[2][1] + bias3[1],
                                             acc0[2][2] + bias3[2], acc0[2][3] + bias3[3]);
        *(float4*)&c[base + 4] = make_float4(acc0[2][4] + bias3[4], acc0[2][5] + bias3[5],
                                             acc0[2][6] + bias3[6], acc0[2][7] + bias3[7]);
        uint4 bw;
        bw.x = bfpack2(acc0[1][0], acc0[1][1]);
        bw.y = bfpack2(acc0[1][2], acc0[1][3]);
        bw.z = bfpack2(acc0[1][4], acc0[1][5]);
        bw.w = bfpack2(acc0[1][6], acc0[1][7]);
        *(uint4*)(bbf + base) = bw;
    }
    if (v1) {
        const size_t base = (size_t)n1 * F_HID + p * 8;
        *(float4*)&a[base]     = make_float4(acc1[0][0] + bias1[0], acc1[0][1] + bias1[1],
                                             acc1[0][2] + bias1[2], acc1[0][3] + bias1[3]);
        *(float4*)&a[base + 4] = make_float4(acc1[0][4] + bias1[4], acc1[0][5] + bias1[5],
                                             acc1[0][6] + bias1[6], acc1[0][7] + bias1[7]);
        *(float4*)&c[base]     = make_float4(acc1[2][0] + bias3[0], acc1[2][1] + bias3[1],
                                             acc1[2][2] + bias3[2], acc1[2][3] + bias3[3]);
        *(float4*)&c[base + 4] = make_float4(acc1[2][4] + bias3[4], acc1[2][5] + bias3[5],
                                             acc1[2][6] + bias3[6], acc1[2][7] + bias3[7]);
        uint4 bw;
        bw.x = bfpack2(acc1[1][0], acc1[1][1]);
        bw.y = bfpack2(acc1[1][2], acc1[1][3]);
        bw.z = bfpack2(acc1[1][4], acc1[1][5]);
        bw.w = bfpack2(acc1[1][6], acc1[1][7]);
        *(uint4*)(bbf + base) = bw;
    }
}

// ---------------- init: zero degw, set gcur[i] = i*SLACK ----------------
__global__ __launch_bounds__(256) void init_kernel(
    float* __restrict__ degw, unsigned int* __restrict__ gcur)
{
    const int n = blockIdx.x * 256 + threadIdx.x;
    if (n < N_NODES) degw[n] = 0.f;
    if (n < NB) gcur[n] = (unsigned int)n * SLACK;
}

// ---------------- partition: edges -> dst-bucket regions (slack-allocated) ----------------
// record: x = (dst_local << 17) | src, y = bits(ew)
__global__ __launch_bounds__(1024) void partition_kernel(
    const int* __restrict__ ei, const float* __restrict__ ea,
    unsigned int* __restrict__ gcur, uint2* __restrict__ packed,
    const unsigned short* __restrict__ bbf,
    float* __restrict__ c, float* __restrict__ degw)
{
    __shared__ unsigned int h[NB], basel[NB], lofs[NB];
    const int tid = threadIdx.x;
    const long long e0 = (long long)blockIdx.x * CHUNKP;
    const int ne = (int)min((long long)CHUNKP, (long long)N_EDGES - e0);

    for (int i = tid; i < NB; i += 1024) { h[i] = 0u; lofs[i] = 0u; }
    __syncthreads();
    for (int i = tid; i < ne; i += 1024)
        atomicAdd(&h[ei[N_EDGES + e0 + i] >> 7], 1u);
    __syncthreads();
    for (int i = tid; i < NB; i += 1024)
        basel[i] = h[i] ? atomicAdd(&gcur[i], h[i]) : 0u;
    __syncthreads();
    for (int i = tid; i < ne; i += 1024) {
        const int   src = ei[e0 + i];
        const int   dst = ei[N_EDGES + e0 + i];
        const float ew  = ea[e0 + i];
        const int   bkt = dst >> 7;
        const unsigned int pos = basel[bkt] + atomicAdd(&lofs[bkt], 1u);
        if (pos < (unsigned int)(bkt + 1) * SLACK) {
            packed[pos] = make_uint2(((unsigned int)(dst & 127) << 17) | (unsigned int)src,
                                     __float_as_uint(ew));
        } else {
            // overflow valve (P ~ 1e-19 per input; exactness-preserving)
            for (int f = 0; f < F_HID; ++f)
                unsafeAtomicAdd(&c[(size_t)dst * F_HID + f],
                                -ew * bflo((unsigned int)bbf[(size_t)src * F_HID + f] << 16));
            unsafeAtomicAdd(&degw[dst], ew);
        }
    }
}

// ---------------- sort_accum_fin: counting sort + accumulate + fused finalize ----------------
__global__ __launch_bounds__(512) void sort_accum_fin_kernel(
    const uint2* __restrict__ packed, const unsigned int* __restrict__ gcur,
    const float* __restrict__ a, const unsigned short* __restrict__ bbf,
    const float* __restrict__ c, const float* __restrict__ degw,
    const float* __restrict__ fc_w, const float* __restrict__ fc_b,
    float* __restrict__ out)
{
    __shared__ uint2 lrec[SLACK];               // 37.4 KB
    __shared__ unsigned int cnt[BKT], scn[BKT], cur[BKT];
    __shared__ unsigned int base[BKT + 1];
    __shared__ float Wf[N_CLS][F_HID];
    __shared__ float Bf[N_CLS];
    const int bkt = blockIdx.x;
    const int tid = threadIdx.x;

    for (int i = tid; i < N_CLS * F_HID; i += 512)
        ((float*)Wf)[i] = fc_w[i];
    if (tid < N_CLS) Bf[tid] = fc_b[tid];

    const unsigned int s0  = (unsigned int)bkt * SLACK;
    const unsigned int cap = s0 + SLACK;
    unsigned int e0 = gcur[bkt];
    if (e0 > cap) e0 = cap;
    const int K = (int)(e0 - s0);

    if (tid < BKT) cnt[tid] = 0u;
    __syncthreads();

    for (int i = tid; i < K; i += 512)
        atomicAdd(&cnt[packed[s0 + i].x >> 17], 1u);
    __syncthreads();
    if (tid < BKT) scn[tid] = cnt[tid];
    __syncthreads();
    for (int d = 1; d < BKT; d <<= 1) {
        unsigned int tv = 0u;
        if (tid < BKT && tid >= d) tv = scn[tid - d];
        __syncthreads();
        if (tid < BKT) scn[tid] += tv;
        __syncthreads();
    }
    if (tid < BKT) {
        base[tid] = scn[tid] - cnt[tid];
        cur[tid]  = scn[tid] - cnt[tid];
    }
    if (tid == 0) base[BKT] = (unsigned int)K;
    __syncthreads();
    for (int i = tid; i < K; i += 512) {
        const uint2 rec = packed[s0 + i];         // L2-hot from count pass
        lrec[atomicAdd(&cur[rec.x >> 17], 1u)] = rec;
    }
    __syncthreads();

    const int q = tid >> 2;
    const int p = tid & 3;
    const int node = bkt * BKT + q;
    if (node >= N_NODES) return;                  // no barriers below

    float4 a0 = make_float4(0.f, 0.f, 0.f, 0.f);
    float4 a1 = make_float4(0.f, 0.f, 0.f, 0.f);
    float dw = degw[node];                        // overflow-valve contribution (usually 0)

    const unsigned int jb = base[q], je = base[q + 1];
    for (unsigned int j = jb; j < je; ++j) {
        const uint2 rec = lrec[j];                // broadcast within quad
        const float ew = __uint_as_float(rec.y);
        const uint4 bv = *(const uint4*)(bbf + (size_t)(rec.x & 0x1FFFFu) * F_HID + p * 8);
        a0.x += ew * bflo(bv.x); a0.y += ew * bfhi(bv.x);
        a0.z += ew * bflo(bv.y); a0.w += ew * bfhi(bv.y);
        a1.x += ew * bflo(bv.z); a1.y += ew * bfhi(bv.z);
        a1.z += ew * bflo(bv.w); a1.w += ew * bfhi(bv.w);
        dw += ew;
    }

    // fused finalize: h = elu(c - acc + dw*a); FC; log_softmax
    const float4* av = (const float4*)(a + (size_t)node * F_HID) + p * 2;
    const float4* cv = (const float4*)(c + (size_t)node * F_HID) + p * 2;
    const float4 A0 = av[0], A1 = av[1], C0 = cv[0], C1 = cv[1];

    float h8[8];
    {
        float t0 = C0.x - a0.x + dw * A0.x;
        float t1 = C0.y - a0.y + dw * A0.y;
        float t2 = C0.z - a0.z + dw * A0.z;
        float t3 = C0.w - a0.w + dw * A0.w;
        float t4 = C1.x - a1.x + dw * A1.x;
        float t5 = C1.y - a1.y + dw * A1.y;
        float t6 = C1.z - a1.z + dw * A1.z;
        float t7 = C1.w - a1.w + dw * A1.w;
        h8[0] = t0 > 0.f ? t0 : expm1f(t0);
        h8[1] = t1 > 0.f ? t1 : expm1f(t1);
        h8[2] = t2 > 0.f ? t2 : expm1f(t2);
        h8[3] = t3 > 0.f ? t3 : expm1f(t3);
        h8[4] = t4 > 0.f ? t4 : expm1f(t4);
        h8[5] = t5 > 0.f ? t5 : expm1f(t5);
        h8[6] = t6 > 0.f ? t6 : expm1f(t6);
        h8[7] = t7 > 0.f ? t7 : expm1f(t7);
    }

    float lg[N_CLS];
#pragma unroll
    for (int j = 0; j < N_CLS; ++j) {
        const float* wr = &Wf[j][p * 8];
        float sm = 0.f;
#pragma unroll
        for (int i = 0; i < 8; ++i) sm += h8[i] * wr[i];
        sm += __shfl_xor(sm, 1, 4);
        sm += __shfl_xor(sm, 2, 4);
        lg[j] = sm + Bf[j];
    }

    float mx = lg[0];
#pragma unroll
    for (int j = 1; j < N_CLS; ++j) mx = fmaxf(mx, lg[j]);
    float se = 0.f;
#pragma unroll
    for (int j = 0; j < N_CLS; ++j) se += expf(lg[j] - mx);
    const float lse = mx + logf(se);

    if (p == 0) {
        float* o = out + (size_t)node * N_CLS;
#pragma unroll
        for (int j = 0; j < N_CLS; ++j) o[j] = lg[j] - lse;
    }
}

// ---------------- fallback: direct atomic edge scatter (bf16 b) ----------------
__global__ __launch_bounds__(256) void edge_scatter_kernel(
    const int* __restrict__ ei, const float* __restrict__ ea,
    const unsigned short* __restrict__ bbf,
    float* __restrict__ c, float* __restrict__ degw)
{
    const long long t = (long long)blockIdx.x * 256 + threadIdx.x;
    const int e = (int)(t >> 2);
    const int p = (int)(t & 3);
    if (e >= N_EDGES) return;

    const int src = ei[e];
    const int dst = ei[N_EDGES + e];
    const float ew = ea[e];

    const uint4 bv = *(const uint4*)(bbf + (size_t)src * F_HID + p * 8);

    float* cd = c + (size_t)dst * F_HID + p * 8;
    unsafeAtomicAdd(&cd[0], -ew * bflo(bv.x));
    unsafeAtomicAdd(&cd[1], -ew * bfhi(bv.x));
    unsafeAtomicAdd(&cd[2], -ew * bflo(bv.y));
    unsafeAtomicAdd(&cd[3], -ew * bfhi(bv.y));
    unsafeAtomicAdd(&cd[4], -ew * bflo(bv.z));
    unsafeAtomicAdd(&cd[5], -ew * bfhi(bv.z));
    unsafeAtomicAdd(&cd[6], -ew * bflo(bv.w));
    unsafeAtomicAdd(&cd[7], -ew * bfhi(bv.w));
    if (p == 0) unsafeAtomicAdd(&degw[dst], ew);
}

// ---------------- finalize (fallback path only) ----------------
__global__ __launch_bounds__(256) void finalize_kernel(
    const float* __restrict__ a, const float* __restrict__ c,
    const float* __restrict__ degw,
    const float* __restrict__ fc_w, const float* __restrict__ fc_b,
    float* __restrict__ out)
{
    __shared__ float Wf[N_CLS][F_HID];
    __shared__ float Bf[N_CLS];
    const int tid = threadIdx.x;
    for (int i = tid; i < N_CLS * F_HID; i += 256)
        ((float*)Wf)[i] = fc_w[i];
    if (tid < N_CLS) Bf[tid] = fc_b[tid];
    __syncthreads();

    const int n = blockIdx.x * 256 + tid;
    if (n >= N_NODES) return;

    const float dw = degw[n];
    const float4* av = (const float4*)(a + (size_t)n * F_HID);
    const float4* cv = (const float4*)(c + (size_t)n * F_HID);

    float h[F_HID];
#pragma unroll
    for (int i = 0; i < F_HID / 4; ++i) {
        float4 A = av[i], C = cv[i];
        float t0 = C.x + dw * A.x;
        float t1 = C.y + dw * A.y;
        float t2 = C.z + dw * A.z;
        float t3 = C.w + dw * A.w;
        h[4 * i + 0] = t0 > 0.f ? t0 : expm1f(t0);
        h[4 * i + 1] = t1 > 0.f ? t1 : expm1f(t1);
        h[4 * i + 2] = t2 > 0.f ? t2 : expm1f(t2);
        h[4 * i + 3] = t3 > 0.f ? t3 : expm1f(t3);
    }

    float logits[N_CLS];
    float mx = -1e30f;
#pragma unroll
    for (int j = 0; j < N_CLS; ++j) {
        float s = Bf[j];
#pragma unroll
        for (int f = 0; f < F_HID; ++f) s += h[f] * Wf[j][f];
        logits[j] = s;
        mx = fmaxf(mx, s);
    }
    float sum = 0.f;
#pragma unroll
    for (int j = 0; j < N_CLS; ++j) sum += expf(logits[j] - mx);
    const float lse = mx + logf(sum);

    float* o = out + (size_t)n * N_CLS;
#pragma unroll
    for (int j = 0; j < N_CLS; ++j) o[j] = logits[j] - lse;
}

extern "C" void kernel_launch(void* const* d_in, const int* in_sizes, int n_in,
                              void* d_out, int out_size, void* d_ws, size_t ws_size,
                              hipStream_t stream) {
    const float* x   = (const float*)d_in[0];
    const int*   ei  = (const int*)d_in[1];
    const float* ea  = (const float*)d_in[2];
    const float* W1  = (const float*)d_in[3];
    const float* b1  = (const float*)d_in[4];
    const float* W2  = (const float*)d_in[5];
    const float* W3  = (const float*)d_in[6];
    const float* b3  = (const float*)d_in[7];
    const float* fcw = (const float*)d_in[8];
    const float* fcb = (const float*)d_in[9];
    float* out = (float*)d_out;

    const size_t NF = (size_t)N_NODES * F_HID;
    float* a             = (float*)d_ws;
    float* c             = a + NF;
    unsigned short* bbf  = (unsigned short*)(c + NF);
    float* degw          = (float*)(bbf + NF);
    unsigned int* gcur   = (unsigned int*)(degw + N_NODES);
    uint2* packed        = (uint2*)(gcur + 1024);   // all prior byte counts divisible by 8

    const size_t need = NF * 4 * 2 + NF * 2 + (size_t)N_NODES * 4 + 4096
                      + (size_t)NB * SLACK * 8;     // ~61.6 MB

    gemm3_kernel<<<(N_NODES + 127) / 128, 256, 0, stream>>>(
        x, W1, b1, W2, W3, b3, a, bbf, c);

    if (ws_size >= need) {
        init_kernel<<<(N_NODES + 255) / 256, 256, 0, stream>>>(degw, gcur);
        partition_kernel<<<NBP, 1024, 0, stream>>>(ei, ea, gcur, packed, bbf, c, degw);
        sort_accum_fin_kernel<<<NB, 512, 0, stream>>>(
            packed, gcur, a, bbf, c, degw, fcw, fcb, out);
    } else {
        init_kernel<<<(N_NODES + 255) / 256, 256, 0, stream>>>(degw, gcur);
        edge_scatter_kernel<<<(int)(((long long)N_EDGES * 4 + 255) / 256), 256, 0, stream>>>(
            ei, ea, bbf, c, degw);
        finalize_kernel<<<(N_NODES + 255) / 256, 256, 0, stream>>>(
            a, c, degw, fcw, fcb, out);
    }
}